// Round 1
// baseline (855.396 us; speedup 1.0000x reference)
//
#include <hip/hip_runtime.h>
#include <hip/hip_bf16.h>
#include <math.h>

// GCN: 3x { aggregate(segment_sum over incoming edges) ; linear(+bias) ; relu }
// last layer: linear to 40 classes + log_softmax, plus scalar node_count output.
//
// Pipeline per call:
//   1. build CSR grouped by dst (histogram -> exclusive scan -> scatter)
//   2. agg1 = seg_sum(features) ; h1 = relu(agg1@W1+b1)
//   3. agg2 = seg_sum(h1)       ; h2 = relu(agg2@W2+b2)
//   4. agg3 = seg_sum(h2)       ; out = log_softmax(agg3@W3+b3)
//   5. out[N*40] = 3*N

// ---------------- CSR build ----------------

__global__ __launch_bounds__(256) void k_count(const int* __restrict__ dst,
                                               int* __restrict__ cnt, int E) {
    int e = blockIdx.x * 256 + threadIdx.x;
    if (e < E) atomicAdd(&cnt[dst[e]], 1);
}

__global__ __launch_bounds__(256) void k_scan1(const int* __restrict__ cnt,
                                               int* __restrict__ inc,
                                               int* __restrict__ bsum, int n) {
    __shared__ int sh[256];
    int t = threadIdx.x;
    int i = blockIdx.x * 256 + t;
    int v = (i < n) ? cnt[i] : 0;
    sh[t] = v;
    __syncthreads();
    for (int s = 1; s < 256; s <<= 1) {
        int x = (t >= s) ? sh[t - s] : 0;
        __syncthreads();
        sh[t] += x;
        __syncthreads();
    }
    if (i < n) inc[i] = sh[t];
    if (t == 255) bsum[blockIdx.x] = sh[255];
}

__global__ __launch_bounds__(256) void k_scan2(const int* __restrict__ bsum,
                                               int* __restrict__ ebo, int nb) {
    __shared__ int sh[256];
    int t = threadIdx.x;
    int v = (t < nb) ? bsum[t] : 0;
    sh[t] = v;
    __syncthreads();
    for (int s = 1; s < 256; s <<= 1) {
        int x = (t >= s) ? sh[t - s] : 0;
        __syncthreads();
        sh[t] += x;
        __syncthreads();
    }
    ebo[t] = sh[t] - v;  // exclusive block offset
}

__global__ __launch_bounds__(256) void k_scan3(const int* __restrict__ inc,
                                               const int* __restrict__ cnt,
                                               const int* __restrict__ ebo,
                                               int* __restrict__ off,
                                               int* __restrict__ pos, int n) {
    int i = blockIdx.x * 256 + threadIdx.x;
    if (i < n) {
        int ib = inc[i] + ebo[blockIdx.x];  // inclusive
        int ex = ib - cnt[i];               // exclusive
        off[i] = ex;
        pos[i] = ex;
        if (i == n - 1) off[n] = ib;
    }
}

__global__ __launch_bounds__(256) void k_scatter(const int* __restrict__ src,
                                                 const int* __restrict__ dst,
                                                 int* __restrict__ pos,
                                                 int* __restrict__ esrc, int E) {
    int e = blockIdx.x * 256 + threadIdx.x;
    if (e < E) {
        int p = atomicAdd(&pos[dst[e]], 1);
        esrc[p] = src[e];
    }
}

// ---------------- aggregation: one wave (64 lanes) per node, float4/lane ----------------

__global__ __launch_bounds__(256) void k_agg(const float* __restrict__ X,
                                             const int* __restrict__ off,
                                             const int* __restrict__ esrc,
                                             float* __restrict__ Y, int n) {
    int wid = blockIdx.x * 4 + (threadIdx.x >> 6);
    int lane = threadIdx.x & 63;
    if (wid >= n) return;
    int s = off[wid], e = off[wid + 1];
    float4 acc = make_float4(0.f, 0.f, 0.f, 0.f);
    const float4* Xv = (const float4*)X;
    for (int i = s; i < e; ++i) {
        int u = esrc[i];
        float4 v = Xv[(size_t)u * 64 + lane];
        acc.x += v.x; acc.y += v.y; acc.z += v.z; acc.w += v.w;
    }
    ((float4*)Y)[(size_t)wid * 64 + lane] = acc;
}

// ---------------- fp32 register-tiled GEMM: (M x 256) @ (256 x 256) + bias [, relu] ----------------
// block = 256 threads, tile 64 rows x 256 cols, K staged in LDS (K_TILE=32).
// thread (tx=t&15, ty=t>>4): 4 rows (ty*4..) x 16 cols (tx*4 + 64*j, j=0..3).

template <int RELU>
__global__ __launch_bounds__(256) void k_gemm256(const float* __restrict__ A,
                                                 const float* __restrict__ W,
                                                 const float* __restrict__ bias,
                                                 float* __restrict__ Y, int M) {
    __shared__ float AsT[32][68];   // [k][row], padded
    __shared__ float Bs[32][264];   // [k][col], padded (row stride 264*4 B, 16B aligned)
    int t = threadIdx.x;
    int tx = t & 15, ty = t >> 4;
    int bm = blockIdx.x * 64;

    float4 acc[4][4];
#pragma unroll
    for (int r = 0; r < 4; ++r)
#pragma unroll
        for (int j = 0; j < 4; ++j) acc[r][j] = make_float4(0.f, 0.f, 0.f, 0.f);

    for (int kt = 0; kt < 8; ++kt) {
        int k0 = kt * 32;
        // stage A tile (64x32), transposed into AsT[k][row]
#pragma unroll
        for (int i = 0; i < 2; ++i) {
            int lid = t + i * 256;       // 0..511
            int row = lid >> 3;          // 0..63
            int kq = lid & 7;            // 0..7 (float4 of k)
            float4 v = make_float4(0.f, 0.f, 0.f, 0.f);
            int gm = bm + row;
            if (gm < M) v = *(const float4*)&A[(size_t)gm * 256 + k0 + kq * 4];
            AsT[kq * 4 + 0][row] = v.x;
            AsT[kq * 4 + 1][row] = v.y;
            AsT[kq * 4 + 2][row] = v.z;
            AsT[kq * 4 + 3][row] = v.w;
        }
        // stage B tile (32x256)
#pragma unroll
        for (int i = 0; i < 8; ++i) {
            int lid = t + i * 256;       // 0..2047
            int k = lid >> 6;            // 0..31
            int c4 = lid & 63;           // 0..63
            float4 v = *(const float4*)&W[(size_t)(k0 + k) * 256 + c4 * 4];
            *(float4*)&Bs[k][c4 * 4] = v;
        }
        __syncthreads();
#pragma unroll
        for (int kk = 0; kk < 32; ++kk) {
            float4 av = *(const float4*)&AsT[kk][ty * 4];
            float4 bv[4];
#pragma unroll
            for (int j = 0; j < 4; ++j) bv[j] = *(const float4*)&Bs[kk][tx * 4 + 64 * j];
            float ar[4] = {av.x, av.y, av.z, av.w};
#pragma unroll
            for (int r = 0; r < 4; ++r) {
#pragma unroll
                for (int j = 0; j < 4; ++j) {
                    acc[r][j].x += ar[r] * bv[j].x;
                    acc[r][j].y += ar[r] * bv[j].y;
                    acc[r][j].z += ar[r] * bv[j].z;
                    acc[r][j].w += ar[r] * bv[j].w;
                }
            }
        }
        __syncthreads();
    }
    // epilogue: +bias, optional relu, store
#pragma unroll
    for (int j = 0; j < 4; ++j) {
        float4 bj = *(const float4*)&bias[tx * 4 + 64 * j];
#pragma unroll
        for (int r = 0; r < 4; ++r) {
            int gm = bm + ty * 4 + r;
            if (gm < M) {
                float4 o;
                o.x = acc[r][j].x + bj.x;
                o.y = acc[r][j].y + bj.y;
                o.z = acc[r][j].z + bj.z;
                o.w = acc[r][j].w + bj.w;
                if (RELU) {
                    o.x = fmaxf(o.x, 0.f); o.y = fmaxf(o.y, 0.f);
                    o.z = fmaxf(o.z, 0.f); o.w = fmaxf(o.w, 0.f);
                }
                *(float4*)&Y[(size_t)gm * 256 + tx * 4 + 64 * j] = o;
            }
        }
    }
}

// ---------------- output layer: (M x 256) @ (256 x 40) + b3 -> log_softmax ----------------
// one wave per node; W3 (40KB) staged in LDS per block; grid-stride over nodes.

__global__ __launch_bounds__(256) void k_out(const float* __restrict__ AGG,
                                             const float* __restrict__ W3,
                                             const float* __restrict__ b3,
                                             float* __restrict__ out, int n,
                                             float node_count) {
    __shared__ float w3s[256 * 40];
    __shared__ float rows[4][256];
    int t = threadIdx.x;
#pragma unroll
    for (int i = 0; i < 10; ++i)
        ((float4*)w3s)[t + i * 256] = ((const float4*)W3)[t + i * 256];
    __syncthreads();

    if (blockIdx.x == 0 && t == 0) out[(size_t)n * 40] = node_count;

    int wslot = t >> 6, lane = t & 63;
    int per_round = gridDim.x * 4;
    int iters = (n + per_round - 1) / per_round;
    for (int it = 0; it < iters; ++it) {
        int node = it * per_round + blockIdx.x * 4 + wslot;
        __syncthreads();
        if (node < n) {
            float4 r = ((const float4*)AGG)[(size_t)node * 64 + lane];
            *(float4*)&rows[wslot][lane * 4] = r;
        }
        __syncthreads();
        if (node < n) {
            float x = -INFINITY;
            if (lane < 40) {
                float acc = b3[lane];
#pragma unroll 8
                for (int k = 0; k < 256; ++k) acc += rows[wslot][k] * w3s[k * 40 + lane];
                x = acc;
            }
            float m = x;
            for (int o = 32; o >= 1; o >>= 1) m = fmaxf(m, __shfl_xor(m, o));
            float ex = (lane < 40) ? expf(x - m) : 0.f;
            float ssum = ex;
            for (int o = 32; o >= 1; o >>= 1) ssum += __shfl_xor(ssum, o);
            if (lane < 40) out[(size_t)node * 40 + lane] = x - m - logf(ssum);
        }
    }
}

// ---------------- launch ----------------

extern "C" void kernel_launch(void* const* d_in, const int* in_sizes, int n_in,
                              void* d_out, int out_size, void* d_ws, size_t ws_size,
                              hipStream_t stream) {
    const float* feat = (const float*)d_in[0];
    const int* ei = (const int*)d_in[1];
    const float* W1 = (const float*)d_in[4];
    const float* b1 = (const float*)d_in[5];
    const float* W2 = (const float*)d_in[6];
    const float* b2 = (const float*)d_in[7];
    const float* W3 = (const float*)d_in[8];
    const float* b3 = (const float*)d_in[9];

    const int N = in_sizes[0] / 256;
    const int E = in_sizes[1] / 2;
    const int* srcs = ei;
    const int* dsts = ei + E;

    char* ws = (char*)d_ws;
    size_t o = 0;
    auto alloc = [&](size_t bytes) {
        size_t r = o;
        o += (bytes + 255) & ~size_t(255);
        return r;
    };
    int* off   = (int*)(ws + alloc((size_t)(N + 1) * 4));
    int* cnt   = (int*)(ws + alloc((size_t)N * 4));
    int* pos   = (int*)(ws + alloc((size_t)N * 4));
    int* inc   = (int*)(ws + alloc((size_t)N * 4));
    int* bsum  = (int*)(ws + alloc(256 * 4));
    int* ebo   = (int*)(ws + alloc(256 * 4));
    int* esrc  = (int*)(ws + alloc((size_t)E * 4));
    float* bufA = (float*)(ws + alloc((size_t)N * 256 * 4));
    float* bufB = (float*)(ws + alloc((size_t)N * 256 * 4));
    (void)ws_size; (void)n_in; (void)out_size;

    const int NB = (N + 255) / 256;  // 196 <= 256, single-block scan2 is fine

    hipMemsetAsync(cnt, 0, (size_t)N * 4, stream);
    k_count<<<(E + 255) / 256, 256, 0, stream>>>(dsts, cnt, E);
    k_scan1<<<NB, 256, 0, stream>>>(cnt, inc, bsum, N);
    k_scan2<<<1, 256, 0, stream>>>(bsum, ebo, NB);
    k_scan3<<<NB, 256, 0, stream>>>(inc, cnt, ebo, off, pos, N);
    k_scatter<<<(E + 255) / 256, 256, 0, stream>>>(srcs, dsts, pos, esrc, E);

    const int aggBlocks = (N + 3) / 4;
    const int gemmBlocks = (N + 63) / 64;

    k_agg<<<aggBlocks, 256, 0, stream>>>(feat, off, esrc, bufA, N);
    k_gemm256<1><<<gemmBlocks, 256, 0, stream>>>(bufA, W1, b1, bufB, N);
    k_agg<<<aggBlocks, 256, 0, stream>>>(bufB, off, esrc, bufA, N);
    k_gemm256<1><<<gemmBlocks, 256, 0, stream>>>(bufA, W2, b2, bufB, N);
    k_agg<<<aggBlocks, 256, 0, stream>>>(bufB, off, esrc, bufA, N);
    k_out<<<2048, 256, 0, stream>>>(bufA, W3, b3, (float*)d_out, N, 3.0f * (float)N);
}

// Round 4
// 517.409 us; speedup vs baseline: 1.6532x; 1.6532x over previous
//
#include <hip/hip_runtime.h>
#include <hip/hip_bf16.h>
#include <math.h>

// GCN bf16 pipeline:
//   CSR build (histogram/scan/scatter)
//   feat -> bf16 ; W1,W2 -> bf16 transposed [N][K]
//   3x { agg = seg_sum(bf16 gather, fp32 acc) -> bf16 ; MFMA GEMM / output layer }
//   out = log_softmax(agg3 @ W3 + b3) fp32 ; out[N*40] = 3N

typedef __attribute__((ext_vector_type(8))) short bf16x8;
typedef __attribute__((ext_vector_type(4))) float f32x4;

static __device__ __forceinline__ short f2b(float f) {
    union { float f; unsigned u; } v; v.f = f;
    unsigned r = (v.u + 0x7FFFu + ((v.u >> 16) & 1u)) >> 16;
    return (short)r;
}
static __device__ __forceinline__ float b2f(short h) {
    union { unsigned u; float f; } v; v.u = ((unsigned)(unsigned short)h) << 16;
    return v.f;
}
static __device__ __forceinline__ bf16x8 bzero8() {
    bf16x8 v;
#pragma unroll
    for (int j = 0; j < 8; ++j) v[j] = 0;
    return v;
}

// ---------------- CSR build ----------------

__global__ __launch_bounds__(256) void k_count(const int* __restrict__ dst,
                                               int* __restrict__ cnt, int E) {
    int e = blockIdx.x * 256 + threadIdx.x;
    if (e < E) atomicAdd(&cnt[dst[e]], 1);
}

__global__ __launch_bounds__(256) void k_scan1(const int* __restrict__ cnt,
                                               int* __restrict__ inc,
                                               int* __restrict__ bsum, int n) {
    __shared__ int sh[256];
    int t = threadIdx.x;
    int i = blockIdx.x * 256 + t;
    int v = (i < n) ? cnt[i] : 0;
    sh[t] = v;
    __syncthreads();
    for (int s = 1; s < 256; s <<= 1) {
        int x = (t >= s) ? sh[t - s] : 0;
        __syncthreads();
        sh[t] += x;
        __syncthreads();
    }
    if (i < n) inc[i] = sh[t];
    if (t == 255) bsum[blockIdx.x] = sh[255];
}

__global__ __launch_bounds__(256) void k_scan2(const int* __restrict__ bsum,
                                               int* __restrict__ ebo, int nb) {
    __shared__ int sh[256];
    int t = threadIdx.x;
    int v = (t < nb) ? bsum[t] : 0;
    sh[t] = v;
    __syncthreads();
    for (int s = 1; s < 256; s <<= 1) {
        int x = (t >= s) ? sh[t - s] : 0;
        __syncthreads();
        sh[t] += x;
        __syncthreads();
    }
    ebo[t] = sh[t] - v;
}

__global__ __launch_bounds__(256) void k_scan3(const int* __restrict__ inc,
                                               const int* __restrict__ cnt,
                                               const int* __restrict__ ebo,
                                               int* __restrict__ off,
                                               int* __restrict__ pos, int n) {
    int i = blockIdx.x * 256 + threadIdx.x;
    if (i < n) {
        int ib = inc[i] + ebo[blockIdx.x];
        int ex = ib - cnt[i];
        off[i] = ex;
        pos[i] = ex;
        if (i == n - 1) off[n] = ib;
    }
}

__global__ __launch_bounds__(256) void k_scatter(const int* __restrict__ src,
                                                 const int* __restrict__ dst,
                                                 int* __restrict__ pos,
                                                 int* __restrict__ esrc, int E) {
    int e = blockIdx.x * 256 + threadIdx.x;
    if (e < E) {
        int p = atomicAdd(&pos[dst[e]], 1);
        esrc[p] = src[e];
    }
}

// ---------------- converts ----------------

__global__ __launch_bounds__(256) void k_cvt(const float* __restrict__ X,
                                             short* __restrict__ Y, int n4) {
    int i = blockIdx.x * 256 + threadIdx.x;
    int stride = gridDim.x * 256;
    for (; i < n4; i += stride) {
        float4 v = ((const float4*)X)[i];
        short4 o;
        o.x = f2b(v.x); o.y = f2b(v.y); o.z = f2b(v.z); o.w = f2b(v.w);
        ((short4*)Y)[i] = o;
    }
}

// Wt[n][k] = bf16(W[k][n]), 256x256
__global__ __launch_bounds__(256) void k_cvt_wT(const float* __restrict__ W,
                                                short* __restrict__ Wt) {
    int idx = blockIdx.x * 256 + threadIdx.x;
    int n = idx >> 8, k = idx & 255;
    Wt[idx] = f2b(W[k * 256 + n]);
}

// ---------------- aggregation: one wave per node, bf16 gather, fp32 acc ----------------

__global__ __launch_bounds__(256) void k_agg_b(const short* __restrict__ X,
                                               const int* __restrict__ off,
                                               const int* __restrict__ esrc,
                                               short* __restrict__ Y, int n) {
    int wid = blockIdx.x * 4 + (threadIdx.x >> 6);
    int lane = threadIdx.x & 63;
    if (wid >= n) return;
    int s = off[wid], e = off[wid + 1];
    float ax = 0.f, ay = 0.f, az = 0.f, aw = 0.f;
    const short4* Xv = (const short4*)X;
    int i = s;
    for (; i + 2 <= e; i += 2) {
        int u0 = esrc[i], u1 = esrc[i + 1];
        short4 v0 = Xv[(size_t)u0 * 64 + lane];
        short4 v1 = Xv[(size_t)u1 * 64 + lane];
        ax += b2f(v0.x) + b2f(v1.x);
        ay += b2f(v0.y) + b2f(v1.y);
        az += b2f(v0.z) + b2f(v1.z);
        aw += b2f(v0.w) + b2f(v1.w);
    }
    if (i < e) {
        short4 v0 = Xv[(size_t)esrc[i] * 64 + lane];
        ax += b2f(v0.x); ay += b2f(v0.y); az += b2f(v0.z); aw += b2f(v0.w);
    }
    short4 o;
    o.x = f2b(ax); o.y = f2b(ay); o.z = f2b(az); o.w = f2b(aw);
    ((short4*)Y)[(size_t)wid * 64 + lane] = o;
}

// ---------------- MFMA GEMM: (M x 256) bf16 @ Wt[N=256][K=256] bf16 + bias, relu -> bf16 ----------------
// block 256 = 4 waves; tile 64 x 256; wave owns 64 x 64 (4x4 frags of 16x16); BK=32.
// LDS stage: sA [g][row][8] (4KB), sB [g][col][8] (16KB); epilogue reuses smem (4x 8KB wave regions).

template <int RELU>
__global__ __launch_bounds__(256) void k_gemm_mfma(const short* __restrict__ A,
                                                   const short* __restrict__ Wt,
                                                   const float* __restrict__ bias,
                                                   short* __restrict__ Y, int M) {
    __shared__ short smem[16384];  // 32 KB
    short* sA = smem;              // 2048 elems
    short* sB = smem + 2048;       // 8192 elems
    const int t = threadIdx.x;
    const int w = t >> 6, l = t & 63;
    const int lg = l >> 4, lr = l & 15;
    const int bm = blockIdx.x * 64;

    f32x4 acc[4][4];
#pragma unroll
    for (int a = 0; a < 4; ++a)
#pragma unroll
        for (int b = 0; b < 4; ++b) {
            acc[a][b][0] = 0.f; acc[a][b][1] = 0.f;
            acc[a][b][2] = 0.f; acc[a][b][3] = 0.f;
        }

    const int arow = bm + (t & 63);
    const int ag = t >> 6;
    const bool aok = (arow < M);

    bf16x8 ra, rb0, rb1, rb2, rb3;
    auto loadRegs = [&](int k0) {
        ra = aok ? *(const bf16x8*)&A[(size_t)arow * 256 + k0 + ag * 8] : bzero8();
        const short* wp = &Wt[(size_t)t * 256 + k0];
        rb0 = *(const bf16x8*)&wp[0];
        rb1 = *(const bf16x8*)&wp[8];
        rb2 = *(const bf16x8*)&wp[16];
        rb3 = *(const bf16x8*)&wp[24];
    };

    loadRegs(0);
    for (int kt = 0; kt < 8; ++kt) {
        __syncthreads();
        *(bf16x8*)&sA[t * 8] = ra;
        *(bf16x8*)&sB[t * 8] = rb0;
        *(bf16x8*)&sB[2048 + t * 8] = rb1;
        *(bf16x8*)&sB[4096 + t * 8] = rb2;
        *(bf16x8*)&sB[6144 + t * 8] = rb3;
        if (kt < 7) loadRegs((kt + 1) * 32);
        __syncthreads();

        bf16x8 af[4], bf[4];
#pragma unroll
        for (int rb = 0; rb < 4; ++rb)
            af[rb] = *(const bf16x8*)&sA[lg * 512 + (rb * 16 + lr) * 8];
#pragma unroll
        for (int cb = 0; cb < 4; ++cb)
            bf[cb] = *(const bf16x8*)&sB[lg * 2048 + ((w * 4 + cb) * 16 + lr) * 8];
#pragma unroll
        for (int rb = 0; rb < 4; ++rb)
#pragma unroll
            for (int cb = 0; cb < 4; ++cb)
                acc[rb][cb] = __builtin_amdgcn_mfma_f32_16x16x32_bf16(
                    af[rb], bf[cb], acc[rb][cb], 0, 0, 0);
    }

    __syncthreads();  // all frag reads done; smem free for epilogue
    short* myreg = smem + w * 4096;  // wave-private [64][64]
#pragma unroll
    for (int cb = 0; cb < 4; ++cb) {
        float bb = bias[w * 64 + cb * 16 + lr];
#pragma unroll
        for (int rb = 0; rb < 4; ++rb)
#pragma unroll
            for (int r = 0; r < 4; ++r) {
                float x = acc[rb][cb][r] + bb;
                if (RELU) x = fmaxf(x, 0.f);
                myreg[(rb * 16 + lg * 4 + r) * 64 + cb * 16 + lr] = f2b(x);
            }
    }
    // wave-private region: no cross-wave barrier needed
#pragma unroll
    for (int j = 0; j < 8; ++j) {
        int row = j * 8 + (l >> 3);
        int grow = bm + row;
        bf16x8 v = *(const bf16x8*)&myreg[(j * 64 + l) * 8];
        if (grow < M)
            *(bf16x8*)&Y[(size_t)grow * 256 + w * 64 + (l & 7) * 8] = v;
    }
}

// ---------------- output layer: (M x 256) bf16 @ W3[256][40] f32 + b3 -> log_softmax f32 ----------------

__global__ __launch_bounds__(256) void k_out(const short* __restrict__ AGG,
                                             const float* __restrict__ W3,
                                             const float* __restrict__ b3,
                                             float* __restrict__ out, int n,
                                             float node_count) {
    __shared__ float w3s[256 * 40];
    __shared__ float rows[4][256];
    int t = threadIdx.x;
#pragma unroll
    for (int i = 0; i < 10; ++i)
        ((float4*)w3s)[t + i * 256] = ((const float4*)W3)[t + i * 256];
    __syncthreads();

    if (blockIdx.x == 0 && t == 0) out[(size_t)n * 40] = node_count;

    int wslot = t >> 6, lane = t & 63;
    int per_round = gridDim.x * 4;
    int iters = (n + per_round - 1) / per_round;
    for (int it = 0; it < iters; ++it) {
        int node = it * per_round + blockIdx.x * 4 + wslot;
        __syncthreads();
        if (node < n) {
            short4 r = ((const short4*)AGG)[(size_t)node * 64 + lane];
            rows[wslot][lane * 4 + 0] = b2f(r.x);
            rows[wslot][lane * 4 + 1] = b2f(r.y);
            rows[wslot][lane * 4 + 2] = b2f(r.z);
            rows[wslot][lane * 4 + 3] = b2f(r.w);
        }
        __syncthreads();
        if (node < n) {
            float x = -INFINITY;
            if (lane < 40) {
                float acc = b3[lane];
#pragma unroll 8
                for (int k = 0; k < 256; ++k) acc += rows[wslot][k] * w3s[k * 40 + lane];
                x = acc;
            }
            float m = x;
            for (int o = 32; o >= 1; o >>= 1) m = fmaxf(m, __shfl_xor(m, o));
            float ex = (lane < 40) ? expf(x - m) : 0.f;
            float ssum = ex;
            for (int o = 32; o >= 1; o >>= 1) ssum += __shfl_xor(ssum, o);
            if (lane < 40) out[(size_t)node * 40 + lane] = x - m - logf(ssum);
        }
    }
}

// ---------------- launch ----------------

extern "C" void kernel_launch(void* const* d_in, const int* in_sizes, int n_in,
                              void* d_out, int out_size, void* d_ws, size_t ws_size,
                              hipStream_t stream) {
    const float* feat = (const float*)d_in[0];
    const int* ei = (const int*)d_in[1];
    const float* W1 = (const float*)d_in[4];
    const float* b1 = (const float*)d_in[5];
    const float* W2 = (const float*)d_in[6];
    const float* b2 = (const float*)d_in[7];
    const float* W3 = (const float*)d_in[8];
    const float* b3 = (const float*)d_in[9];

    const int N = in_sizes[0] / 256;
    const int E = in_sizes[1] / 2;
    const int* srcs = ei;
    const int* dsts = ei + E;

    char* ws = (char*)d_ws;
    size_t o = 0;
    auto alloc = [&](size_t bytes) {
        size_t r = o;
        o += (bytes + 255) & ~size_t(255);
        return r;
    };
    int* off    = (int*)(ws + alloc((size_t)(N + 1) * 4));
    int* cnt    = (int*)(ws + alloc((size_t)N * 4));
    int* pos    = (int*)(ws + alloc((size_t)N * 4));
    int* inc    = (int*)(ws + alloc((size_t)N * 4));
    int* bsum   = (int*)(ws + alloc(256 * 4));
    int* ebo    = (int*)(ws + alloc(256 * 4));
    int* esrc   = (int*)(ws + alloc((size_t)E * 4));
    short* featb = (short*)(ws + alloc((size_t)N * 256 * 2));
    short* bufA  = (short*)(ws + alloc((size_t)N * 256 * 2));
    short* bufB  = (short*)(ws + alloc((size_t)N * 256 * 2));
    short* Wt1   = (short*)(ws + alloc(256 * 256 * 2));
    short* Wt2   = (short*)(ws + alloc(256 * 256 * 2));
    (void)ws_size; (void)n_in; (void)out_size;

    const int NB = (N + 255) / 256;

    hipMemsetAsync(cnt, 0, (size_t)N * 4, stream);
    k_count<<<(E + 255) / 256, 256, 0, stream>>>(dsts, cnt, E);
    k_scan1<<<NB, 256, 0, stream>>>(cnt, inc, bsum, N);
    k_scan2<<<1, 256, 0, stream>>>(bsum, ebo, NB);
    k_scan3<<<NB, 256, 0, stream>>>(inc, cnt, ebo, off, pos, N);
    k_scatter<<<(E + 255) / 256, 256, 0, stream>>>(srcs, dsts, pos, esrc, E);

    k_cvt<<<2048, 256, 0, stream>>>(feat, featb, N * 64);
    k_cvt_wT<<<256, 256, 0, stream>>>(W1, Wt1);
    k_cvt_wT<<<256, 256, 0, stream>>>(W2, Wt2);

    const int aggBlocks = (N + 3) / 4;
    const int gemmBlocks = (N + 63) / 64;

    k_agg_b<<<aggBlocks, 256, 0, stream>>>(featb, off, esrc, bufA, N);
    k_gemm_mfma<1><<<gemmBlocks, 256, 0, stream>>>(bufA, Wt1, b1, bufB, N);
    k_agg_b<<<aggBlocks, 256, 0, stream>>>(bufB, off, esrc, bufA, N);
    k_gemm_mfma<1><<<gemmBlocks, 256, 0, stream>>>(bufA, Wt2, b2, bufB, N);
    k_agg_b<<<aggBlocks, 256, 0, stream>>>(bufB, off, esrc, bufA, N);
    k_out<<<2048, 256, 0, stream>>>(bufA, W3, b3, (float*)d_out, N, 3.0f * (float)N);
}

// Round 7
// 427.881 us; speedup vs baseline: 1.9991x; 1.2092x over previous
//
#include <hip/hip_runtime.h>
#include <hip/hip_bf16.h>
#include <math.h>

// GCN bf16 pipeline (round 4):
//   CSR build (histogram/scan/scatter)
//   feat -> bf16 ; W1,W2 -> bf16 transposed [N][K] ; W3 -> bf16 transposed padded [64][256]
//   agg1 = seg_sum(featb) ; h1 = relu(agg1@W1+b1)      (MFMA)
//   agg2 = seg_sum(h1)    ; h2 = relu(agg2@W2+b2)      (MFMA)
//   P = h2 @ W3 (no bias)                               (MFMA, B in regs)
//   out = log_softmax(seg_sum(P) + b3) ; out[N*40] = 3N (fused gather+softmax)
// Uses linearity: agg(X)@W == agg(X@W); applied to layer 3 so the gather is 40-wide.

typedef __attribute__((ext_vector_type(8))) short bf16x8;
typedef __attribute__((ext_vector_type(4))) float f32x4;

static __device__ __forceinline__ short f2b(float f) {
    union { float f; unsigned u; } v; v.f = f;
    unsigned r = (v.u + 0x7FFFu + ((v.u >> 16) & 1u)) >> 16;
    return (short)r;
}
static __device__ __forceinline__ float b2f(short h) {
    union { unsigned u; float f; } v; v.u = ((unsigned)(unsigned short)h) << 16;
    return v.f;
}
static __device__ __forceinline__ bf16x8 bzero8() {
    bf16x8 v;
#pragma unroll
    for (int j = 0; j < 8; ++j) v[j] = 0;
    return v;
}

// ---------------- CSR build ----------------

__global__ __launch_bounds__(256) void k_count(const int* __restrict__ dst,
                                               int* __restrict__ cnt, int E) {
    int e = blockIdx.x * 256 + threadIdx.x;
    if (e < E) atomicAdd(&cnt[dst[e]], 1);
}

__global__ __launch_bounds__(256) void k_scan1(const int* __restrict__ cnt,
                                               int* __restrict__ inc,
                                               int* __restrict__ bsum, int n) {
    __shared__ int sh[256];
    int t = threadIdx.x;
    int i = blockIdx.x * 256 + t;
    int v = (i < n) ? cnt[i] : 0;
    sh[t] = v;
    __syncthreads();
    for (int s = 1; s < 256; s <<= 1) {
        int x = (t >= s) ? sh[t - s] : 0;
        __syncthreads();
        sh[t] += x;
        __syncthreads();
    }
    if (i < n) inc[i] = sh[t];
    if (t == 255) bsum[blockIdx.x] = sh[255];
}

__global__ __launch_bounds__(256) void k_scan2(const int* __restrict__ bsum,
                                               int* __restrict__ ebo, int nb) {
    __shared__ int sh[256];
    int t = threadIdx.x;
    int v = (t < nb) ? bsum[t] : 0;
    sh[t] = v;
    __syncthreads();
    for (int s = 1; s < 256; s <<= 1) {
        int x = (t >= s) ? sh[t - s] : 0;
        __syncthreads();
        sh[t] += x;
        __syncthreads();
    }
    ebo[t] = sh[t] - v;
}

__global__ __launch_bounds__(256) void k_scan3(const int* __restrict__ inc,
                                               const int* __restrict__ cnt,
                                               const int* __restrict__ ebo,
                                               int* __restrict__ off,
                                               int* __restrict__ pos, int n) {
    int i = blockIdx.x * 256 + threadIdx.x;
    if (i < n) {
        int ib = inc[i] + ebo[blockIdx.x];
        int ex = ib - cnt[i];
        off[i] = ex;
        pos[i] = ex;
        if (i == n - 1) off[n] = ib;
    }
}

__global__ __launch_bounds__(256) void k_scatter(const int* __restrict__ src,
                                                 const int* __restrict__ dst,
                                                 int* __restrict__ pos,
                                                 int* __restrict__ esrc, int E) {
    int e = blockIdx.x * 256 + threadIdx.x;
    if (e < E) {
        int p = atomicAdd(&pos[dst[e]], 1);
        esrc[p] = src[e];
    }
}

// ---------------- converts ----------------

__global__ __launch_bounds__(256) void k_cvt(const float* __restrict__ X,
                                             short* __restrict__ Y, int n4) {
    int i = blockIdx.x * 256 + threadIdx.x;
    int stride = gridDim.x * 256;
    for (; i < n4; i += stride) {
        float4 v = ((const float4*)X)[i];
        short4 o;
        o.x = f2b(v.x); o.y = f2b(v.y); o.z = f2b(v.z); o.w = f2b(v.w);
        ((short4*)Y)[i] = o;
    }
}

// Wt[n][k] = bf16(W[k][n]), 256x256
__global__ __launch_bounds__(256) void k_cvt_wT(const float* __restrict__ W,
                                                short* __restrict__ Wt) {
    int idx = blockIdx.x * 256 + threadIdx.x;
    int n = idx >> 8, k = idx & 255;
    Wt[idx] = f2b(W[k * 256 + n]);
}

// Wt3p[c][k] = c<40 ? bf16(W3[k][c]) : 0 ; 64x256
__global__ __launch_bounds__(256) void k_cvt_wT3(const float* __restrict__ W3,
                                                 short* __restrict__ Wt3p) {
    int idx = blockIdx.x * 256 + threadIdx.x;  // 64 blocks
    int c = idx >> 8, k = idx & 255;
    Wt3p[idx] = (c < 40) ? f2b(W3[k * 40 + c]) : (short)0;
}

// ---------------- aggregation (256-wide): one wave per node, bf16 gather, fp32 acc ----------------

__global__ __launch_bounds__(256) void k_agg_b(const short* __restrict__ X,
                                               const int* __restrict__ off,
                                               const int* __restrict__ esrc,
                                               short* __restrict__ Y, int n) {
    int wid = blockIdx.x * 4 + (threadIdx.x >> 6);
    int lane = threadIdx.x & 63;
    if (wid >= n) return;
    int s = off[wid], e = off[wid + 1];
    float ax = 0.f, ay = 0.f, az = 0.f, aw = 0.f;
    const short4* Xv = (const short4*)X;
    int i = s;
    for (; i + 2 <= e; i += 2) {
        int u0 = esrc[i], u1 = esrc[i + 1];
        short4 v0 = Xv[(size_t)u0 * 64 + lane];
        short4 v1 = Xv[(size_t)u1 * 64 + lane];
        ax += b2f(v0.x) + b2f(v1.x);
        ay += b2f(v0.y) + b2f(v1.y);
        az += b2f(v0.z) + b2f(v1.z);
        aw += b2f(v0.w) + b2f(v1.w);
    }
    if (i < e) {
        short4 v0 = Xv[(size_t)esrc[i] * 64 + lane];
        ax += b2f(v0.x); ay += b2f(v0.y); az += b2f(v0.z); aw += b2f(v0.w);
    }
    short4 o;
    o.x = f2b(ax); o.y = f2b(ay); o.z = f2b(az); o.w = f2b(aw);
    ((short4*)Y)[(size_t)wid * 64 + lane] = o;
}

// ---------------- MFMA GEMM: (M x 256) bf16 @ Wt[256][256] bf16 + bias, relu -> bf16 ----------------

template <int RELU>
__global__ __launch_bounds__(256) void k_gemm_mfma(const short* __restrict__ A,
                                                   const short* __restrict__ Wt,
                                                   const float* __restrict__ bias,
                                                   short* __restrict__ Y, int M) {
    __shared__ short smem[16384];  // 32 KB
    short* sA = smem;              // 2048 elems
    short* sB = smem + 2048;       // 8192 elems
    const int t = threadIdx.x;
    const int w = t >> 6, l = t & 63;
    const int lg = l >> 4, lr = l & 15;
    const int bm = blockIdx.x * 64;

    f32x4 acc[4][4];
#pragma unroll
    for (int a = 0; a < 4; ++a)
#pragma unroll
        for (int b = 0; b < 4; ++b) {
            acc[a][b][0] = 0.f; acc[a][b][1] = 0.f;
            acc[a][b][2] = 0.f; acc[a][b][3] = 0.f;
        }

    const int arow = bm + (t & 63);
    const int ag = t >> 6;
    const bool aok = (arow < M);

    bf16x8 ra, rb0, rb1, rb2, rb3;
    auto loadRegs = [&](int k0) {
        ra = aok ? *(const bf16x8*)&A[(size_t)arow * 256 + k0 + ag * 8] : bzero8();
        const short* wp = &Wt[(size_t)t * 256 + k0];
        rb0 = *(const bf16x8*)&wp[0];
        rb1 = *(const bf16x8*)&wp[8];
        rb2 = *(const bf16x8*)&wp[16];
        rb3 = *(const bf16x8*)&wp[24];
    };

    loadRegs(0);
    for (int kt = 0; kt < 8; ++kt) {
        __syncthreads();
        *(bf16x8*)&sA[t * 8] = ra;
        *(bf16x8*)&sB[t * 8] = rb0;
        *(bf16x8*)&sB[2048 + t * 8] = rb1;
        *(bf16x8*)&sB[4096 + t * 8] = rb2;
        *(bf16x8*)&sB[6144 + t * 8] = rb3;
        if (kt < 7) loadRegs((kt + 1) * 32);
        __syncthreads();

        bf16x8 af[4], bf[4];
#pragma unroll
        for (int rb = 0; rb < 4; ++rb)
            af[rb] = *(const bf16x8*)&sA[lg * 512 + (rb * 16 + lr) * 8];
#pragma unroll
        for (int cb = 0; cb < 4; ++cb)
            bf[cb] = *(const bf16x8*)&sB[lg * 2048 + ((w * 4 + cb) * 16 + lr) * 8];
#pragma unroll
        for (int rb = 0; rb < 4; ++rb)
#pragma unroll
            for (int cb = 0; cb < 4; ++cb)
                acc[rb][cb] = __builtin_amdgcn_mfma_f32_16x16x32_bf16(
                    af[rb], bf[cb], acc[rb][cb], 0, 0, 0);
    }

    __syncthreads();
    short* myreg = smem + w * 4096;  // wave-private [64][64]
#pragma unroll
    for (int cb = 0; cb < 4; ++cb) {
        float bb = bias[w * 64 + cb * 16 + lr];
#pragma unroll
        for (int rb = 0; rb < 4; ++rb)
#pragma unroll
            for (int r = 0; r < 4; ++r) {
                float x = acc[rb][cb][r] + bb;
                if (RELU) x = fmaxf(x, 0.f);
                myreg[(rb * 16 + lg * 4 + r) * 64 + cb * 16 + lr] = f2b(x);
            }
    }
#pragma unroll
    for (int j = 0; j < 8; ++j) {
        int row = j * 8 + (l >> 3);
        int grow = bm + row;
        bf16x8 v = *(const bf16x8*)&myreg[(j * 64 + l) * 8];
        if (grow < M)
            *(bf16x8*)&Y[(size_t)grow * 256 + w * 64 + (l & 7) * 8] = v;
    }
}

// ---------------- P GEMM: (M x 256) bf16 @ Wt3p[64][256] bf16 -> P (M x 64) bf16, no bias ----------------
// block 256 = 4 waves; tile 64 rows x 64 cols; wave w owns cols [w*16, w*16+16), 4 row-frags.
// B held fully in registers (8 x bf16x8 per lane); A staged in LDS per 32-wide K step.

__global__ __launch_bounds__(256) void k_gemmP(const short* __restrict__ A,
                                               const short* __restrict__ Wt3p,
                                               short* __restrict__ P, int M) {
    __shared__ short sA[2048];  // [g][row][8], 4 KB
    const int t = threadIdx.x;
    const int w = t >> 6, l = t & 63;
    const int lg = l >> 4, lr = l & 15;
    const int bm = blockIdx.x * 64;

    // B fragments for all 8 K-steps, in registers
    bf16x8 bfr[8];
#pragma unroll
    for (int kt = 0; kt < 8; ++kt)
        bfr[kt] = *(const bf16x8*)&Wt3p[(size_t)(w * 16 + lr) * 256 + kt * 32 + lg * 8];

    f32x4 acc[4];
#pragma unroll
    for (int a = 0; a < 4; ++a) {
        acc[a][0] = 0.f; acc[a][1] = 0.f; acc[a][2] = 0.f; acc[a][3] = 0.f;
    }

    const int arow = bm + l;
    const bool aok = (arow < M);
    bf16x8 ra = aok ? *(const bf16x8*)&A[(size_t)arow * 256 + w * 8] : bzero8();

#pragma unroll
    for (int kt = 0; kt < 8; ++kt) {
        __syncthreads();
        *(bf16x8*)&sA[t * 8] = ra;
        if (kt < 7)
            ra = aok ? *(const bf16x8*)&A[(size_t)arow * 256 + (kt + 1) * 32 + w * 8]
                     : bzero8();
        __syncthreads();
        bf16x8 af[4];
#pragma unroll
        for (int rb = 0; rb < 4; ++rb)
            af[rb] = *(const bf16x8*)&sA[lg * 512 + (rb * 16 + lr) * 8];
#pragma unroll
        for (int rb = 0; rb < 4; ++rb)
            acc[rb] = __builtin_amdgcn_mfma_f32_16x16x32_bf16(af[rb], bfr[kt], acc[rb], 0, 0, 0);
    }

    // store: frag rb -> rows bm + rb*16 + lg*4 + r, col w*16 + lr
#pragma unroll
    for (int rb = 0; rb < 4; ++rb)
#pragma unroll
        for (int r = 0; r < 4; ++r) {
            int grow = bm + rb * 16 + lg * 4 + r;
            if (grow < M)
                P[(size_t)grow * 64 + w * 16 + lr] = f2b(acc[rb][r]);
        }
}

// ---------------- fused agg3 + bias + log_softmax: one wave per node ----------------
// lane f accumulates P[:, f] over incoming edges (P row = 128 B, one coalesced line/edge).

__global__ __launch_bounds__(256) void k_aggout(const short* __restrict__ P,
                                                const int* __restrict__ off,
                                                const int* __restrict__ esrc,
                                                const float* __restrict__ b3,
                                                float* __restrict__ out, int n,
                                                float node_count) {
    if (blockIdx.x == 0 && threadIdx.x == 0) out[(size_t)n * 40] = node_count;
    int wid = blockIdx.x * 4 + (threadIdx.x >> 6);
    int lane = threadIdx.x & 63;
    if (wid >= n) return;
    int s = off[wid], e = off[wid + 1];
    float acc = 0.f;
    int i = s;
    for (; i + 4 <= e; i += 4) {
        int u0 = esrc[i], u1 = esrc[i + 1], u2 = esrc[i + 2], u3 = esrc[i + 3];
        acc += b2f(P[(size_t)u0 * 64 + lane]) + b2f(P[(size_t)u1 * 64 + lane]) +
               b2f(P[(size_t)u2 * 64 + lane]) + b2f(P[(size_t)u3 * 64 + lane]);
    }
    for (; i < e; ++i) acc += b2f(P[(size_t)esrc[i] * 64 + lane]);

    float x = (lane < 40) ? acc + b3[lane] : -INFINITY;
    float m = x;
    for (int o = 32; o >= 1; o >>= 1) m = fmaxf(m, __shfl_xor(m, o));
    float ex = (lane < 40) ? expf(x - m) : 0.f;
    float ss = ex;
    for (int o = 32; o >= 1; o >>= 1) ss += __shfl_xor(ss, o);
    if (lane < 40) out[(size_t)wid * 40 + lane] = x - m - logf(ss);
}

// ---------------- launch ----------------

extern "C" void kernel_launch(void* const* d_in, const int* in_sizes, int n_in,
                              void* d_out, int out_size, void* d_ws, size_t ws_size,
                              hipStream_t stream) {
    const float* feat = (const float*)d_in[0];
    const int* ei = (const int*)d_in[1];
    const float* W1 = (const float*)d_in[4];
    const float* b1 = (const float*)d_in[5];
    const float* W2 = (const float*)d_in[6];
    const float* b2 = (const float*)d_in[7];
    const float* W3 = (const float*)d_in[8];
    const float* b3 = (const float*)d_in[9];

    const int N = in_sizes[0] / 256;
    const int E = in_sizes[1] / 2;
    const int* srcs = ei;
    const int* dsts = ei + E;

    char* ws = (char*)d_ws;
    size_t o = 0;
    auto alloc = [&](size_t bytes) {
        size_t r = o;
        o += (bytes + 255) & ~size_t(255);
        return r;
    };
    int* off    = (int*)(ws + alloc((size_t)(N + 1) * 4));
    int* cnt    = (int*)(ws + alloc((size_t)N * 4));
    int* pos    = (int*)(ws + alloc((size_t)N * 4));
    int* inc    = (int*)(ws + alloc((size_t)N * 4));
    int* bsum   = (int*)(ws + alloc(256 * 4));
    int* ebo    = (int*)(ws + alloc(256 * 4));
    int* esrc   = (int*)(ws + alloc((size_t)E * 4));
    short* featb = (short*)(ws + alloc((size_t)N * 256 * 2));
    short* bufA  = (short*)(ws + alloc((size_t)N * 256 * 2));
    short* bufB  = (short*)(ws + alloc((size_t)N * 256 * 2));
    short* Wt1   = (short*)(ws + alloc(256 * 256 * 2));
    short* Wt2   = (short*)(ws + alloc(256 * 256 * 2));
    short* Wt3p  = (short*)(ws + alloc(64 * 256 * 2));
    short* Pbuf  = (short*)(ws + alloc((size_t)N * 64 * 2));
    (void)ws_size; (void)n_in; (void)out_size;

    const int NB = (N + 255) / 256;

    hipMemsetAsync(cnt, 0, (size_t)N * 4, stream);
    k_count<<<(E + 255) / 256, 256, 0, stream>>>(dsts, cnt, E);
    k_scan1<<<NB, 256, 0, stream>>>(cnt, inc, bsum, N);
    k_scan2<<<1, 256, 0, stream>>>(bsum, ebo, NB);
    k_scan3<<<NB, 256, 0, stream>>>(inc, cnt, ebo, off, pos, N);
    k_scatter<<<(E + 255) / 256, 256, 0, stream>>>(srcs, dsts, pos, esrc, E);

    k_cvt<<<2048, 256, 0, stream>>>(feat, featb, N * 64);
    k_cvt_wT<<<256, 256, 0, stream>>>(W1, Wt1);
    k_cvt_wT<<<256, 256, 0, stream>>>(W2, Wt2);
    k_cvt_wT3<<<64, 256, 0, stream>>>(W3, Wt3p);

    const int aggBlocks = (N + 3) / 4;
    const int gemmBlocks = (N + 63) / 64;

    k_agg_b<<<aggBlocks, 256, 0, stream>>>(featb, off, esrc, bufA, N);
    k_gemm_mfma<1><<<gemmBlocks, 256, 0, stream>>>(bufA, Wt1, b1, bufB, N);
    k_agg_b<<<aggBlocks, 256, 0, stream>>>(bufB, off, esrc, bufA, N);
    k_gemm_mfma<1><<<gemmBlocks, 256, 0, stream>>>(bufA, Wt2, b2, bufB, N);
    k_gemmP<<<gemmBlocks, 256, 0, stream>>>(bufB, Wt3p, Pbuf, N);
    k_aggout<<<aggBlocks, 256, 0, stream>>>(Pbuf, off, esrc, b3, (float*)d_out, N, 3.0f * (float)N);
}